// Round 17
// baseline (229.748 us; speedup 1.0000x reference)
//
#include <hip/hip_runtime.h>

typedef unsigned short u16;
typedef unsigned int u32;
typedef __attribute__((ext_vector_type(8))) short short8_t;
typedef __attribute__((ext_vector_type(4))) float f32x4;

#define HID 2048
#define KVH 512
#define NROW 4096   // B*S
#define SC2 0.18033688011112042f   // (1/sqrt(64)) * log2(e)

__device__ __forceinline__ u16 f2bf(float f){
  u32 u = __builtin_bit_cast(u32, f);
  u += 0x7fffu + ((u >> 16) & 1u);   // round-to-nearest-even
  return (u16)(u >> 16);
}
__device__ __forceinline__ u32 cvtpk_bf16(float lo, float hi){
  u32 r; asm("v_cvt_pk_bf16_f32 %0, %1, %2" : "=v"(r) : "v"(lo), "v"(hi)); return r;
}

union FragAB { short8_t v; uint4 u4; uint2 q[2]; };

__device__ __forceinline__ void gload_lds16(const u16* g, u16* l){
  __builtin_amdgcn_global_load_lds((const __attribute__((address_space(1))) void*)g,
                                   (__attribute__((address_space(3))) void*)l, 16, 0, 0);
}

// ---------- prep: fused fp32->bf16 convert (z=4) + all four W transposes (z=0..3) ----------
__global__ __launch_bounds__(256)
void prep_all(const float* __restrict__ X, u16* __restrict__ Xb,
              const float* __restrict__ Wq, const float* __restrict__ Wk,
              const float* __restrict__ Wv, const float* __restrict__ Wo,
              u16* __restrict__ Tq, u16* __restrict__ Tk,
              u16* __restrict__ Tv, u16* __restrict__ To)
{
  const int z = blockIdx.z;
  if (z == 4) {   // conv: 4096 blocks x 512 float4 = 2M float4 exact
    int bid = blockIdx.y * 64 + blockIdx.x;
    int i0 = bid * 512 + threadIdx.x;
    #pragma unroll
    for (int it = 0; it < 2; ++it) {
      int i = i0 + it * 256;
      float4 v = ((const float4*)X)[i];
      ushort4 hx; hx.x = f2bf(v.x); hx.y = f2bf(v.y); hx.z = f2bf(v.z); hx.w = f2bf(v.w);
      ((ushort4*)Xb)[i] = hx;
    }
    return;
  }
  __shared__ float tile[32][33];
  const float* W; u16* T; int N;
  if (z == 0)      { W = Wq; T = Tq; N = HID; }
  else if (z == 1) { W = Wk; T = Tk; N = KVH; }
  else if (z == 2) { W = Wv; T = Tv; N = KVH; }
  else             { W = Wo; T = To; N = HID; }
  if ((int)blockIdx.x * 32 >= N) return;
  const int tx = threadIdx.x & 31, ty = threadIdx.x >> 5;
  int x = blockIdx.x * 32 + tx;
  int y0 = blockIdx.y * 32;
  #pragma unroll
  for (int j = ty; j < 32; j += 8)
    tile[j][tx] = W[(size_t)(y0 + j) * N + x];
  __syncthreads();
  #pragma unroll
  for (int j = ty; j < 32; j += 8)
    T[(size_t)(blockIdx.x * 32 + j) * HID + y0 + tx] = f2bf(tile[tx][j]);
}

// ---------- 8-phase 256x256 GEMM (fused QKV) — unchanged from R14 ----------
__global__ __launch_bounds__(512)
void gemm_8ph(const u16* __restrict__ A, const u16* __restrict__ B0,
              const u16* __restrict__ B1, const u16* __restrict__ B2,
              u16* __restrict__ C0, u16* __restrict__ C1, u16* __restrict__ C2)
{
  __shared__ __align__(16) u16 lds_[2 * 32768];   // 128 KB
  const int t = threadIdx.x, lane = t & 63;
  const int w = t >> 6, wm = w >> 2, wn = w & 3;   // 2M x 4N
  const int r = lane & 15, g = lane >> 4;
  const int m0 = blockIdx.y * 256;

  const u16* Bt; u16* Cp; int n0, mode;
  {
    const int bx = blockIdx.x;
    if (bx < 8)       { Bt = B0; Cp = C0; n0 = bx * 256;        mode = 0; }
    else if (bx < 10) { Bt = B1; Cp = C1; n0 = (bx - 8) * 256;  mode = 1; }
    else              { Bt = B2; Cp = C2; n0 = (bx - 10) * 256; mode = 2; }
  }

  f32x4 accL[4][4], accH[4][4];
  #pragma unroll
  for (int i = 0; i < 4; i++)
    #pragma unroll
    for (int j = 0; j < 4; j++) {
      accL[i][j] = (f32x4){0.f, 0.f, 0.f, 0.f};
      accH[i][j] = (f32x4){0.f, 0.f, 0.f, 0.f};
    }

  const int srow = t >> 3, sgr = t & 7;
  auto gA = [&](int kt, int gi) {
    int row = gi * 64 + srow;
    int sg = sgr ^ (row & 7);
    gload_lds16(A + (size_t)(m0 + row) * HID + kt * 64 + sg * 8,
                lds_ + (kt & 1) * 32768 + row * 64 + sgr * 8);
  };
  auto gB = [&](int kt, int gi) {
    int row = gi * 64 + srow;
    int sg = sgr ^ (row & 7);
    gload_lds16(Bt + (size_t)(n0 + row) * HID + kt * 64 + sg * 8,
                lds_ + (kt & 1) * 32768 + 16384 + row * 64 + sgr * 8);
  };

  FragAB a[4], b0[4], b1[4];
  auto readA = [&](int kt, int mlo, int kk) {
    const u16* Ab = lds_ + (kt & 1) * 32768;
    #pragma unroll
    for (int i = 0; i < 4; i++) {
      int row = wm * 128 + (mlo + i) * 16 + r;
      int pg = (kk * 4 + g) ^ (row & 7);
      a[i].u4 = *(const uint4*)&Ab[row * 64 + pg * 8];
    }
  };
  auto readB = [&](int kt, int kk, FragAB (&bf)[4]) {
    const u16* Bb = lds_ + (kt & 1) * 32768 + 16384;
    #pragma unroll
    for (int ni = 0; ni < 4; ni++) {
      int row = wn * 64 + ni * 16 + r;
      int pg = (kk * 4 + g) ^ (row & 7);
      bf[ni].u4 = *(const uint4*)&Bb[row * 64 + pg * 8];
    }
  };

#define MFQ(BF, ACC)                                                          \
  __builtin_amdgcn_s_setprio(1);                                              \
  _Pragma("unroll")                                                           \
  for (int mi = 0; mi < 4; mi++)                                              \
    _Pragma("unroll")                                                         \
    for (int ni = 0; ni < 4; ni++)                                            \
      ACC[mi][ni] = __builtin_amdgcn_mfma_f32_16x16x32_bf16(a[mi].v, BF[ni].v, ACC[mi][ni], 0, 0, 0); \
  __builtin_amdgcn_s_setprio(0);

  const int NT = HID / 64;   // 32 K-tiles
  gB(0, 0); gB(0, 1); gB(0, 2); gB(0, 3);
  gA(0, 0); gA(0, 2); gA(0, 1); gA(0, 3);
  asm volatile("s_waitcnt vmcnt(2)" ::: "memory");
  __builtin_amdgcn_s_barrier();

  for (int kt = 0; kt < NT; ++kt) {
    const bool more = (kt + 1 < NT);
    readB(kt, 0, b0); readA(kt, 0, 0);
    if (more) { gB(kt + 1, 0); gB(kt + 1, 1); }
    __builtin_amdgcn_s_barrier();
    __builtin_amdgcn_sched_barrier(0);
    MFQ(b0, accL)
    __builtin_amdgcn_s_barrier();
    readB(kt, 1, b1); readA(kt, 0, 1);
    if (more) { gB(kt + 1, 2); gB(kt + 1, 3); }
    __builtin_amdgcn_s_barrier();
    __builtin_amdgcn_sched_barrier(0);
    MFQ(b1, accL)
    if (more) asm volatile("s_waitcnt vmcnt(4)" ::: "memory");
    else      asm volatile("s_waitcnt vmcnt(0)" ::: "memory");
    __builtin_amdgcn_s_barrier();
    readA(kt, 4, 0);
    if (more) { gA(kt + 1, 0); gA(kt + 1, 2); }
    __builtin_amdgcn_s_barrier();
    __builtin_amdgcn_sched_barrier(0);
    MFQ(b0, accH)
    __builtin_amdgcn_s_barrier();
    readA(kt, 4, 1);
    if (more) { gA(kt + 1, 1); gA(kt + 1, 3); }
    __builtin_amdgcn_s_barrier();
    __builtin_amdgcn_sched_barrier(0);
    MFQ(b1, accH)
    asm volatile("s_waitcnt vmcnt(2)" ::: "memory");
    __builtin_amdgcn_s_barrier();
  }
#undef MFQ

#define EPI(ACC, MOFF)                                                        \
  _Pragma("unroll")                                                           \
  for (int mi = 0; mi < 4; mi++) {                                            \
    int row = m0 + wm * 128 + (mi + MOFF) * 16 + g * 4;                       \
    _Pragma("unroll")                                                         \
    for (int ni = 0; ni < 4; ni++) {                                          \
      int col = n0 + wn * 64 + ni * 16 + r;                                   \
      if (mode == 2) {                                                        \
        ushort4 hv;                                                           \
        hv.x = f2bf(ACC[mi][ni][0]); hv.y = f2bf(ACC[mi][ni][1]);             \
        hv.z = f2bf(ACC[mi][ni][2]); hv.w = f2bf(ACC[mi][ni][3]);             \
        *(ushort4*)&Cp[(size_t)col * NROW + row] = hv;                        \
      } else {                                                                \
        const int Nout = (mode == 0) ? HID : KVH;                             \
        const float sc = (mode == 0) ? SC2 : 1.f;                             \
        _Pragma("unroll")                                                     \
        for (int rr = 0; rr < 4; rr++)                                        \
          Cp[(size_t)(row + rr) * Nout + col] = f2bf(ACC[mi][ni][rr] * sc);   \
      }                                                                       \
    }                                                                         \
  }
  EPI(accL, 0)
  EPI(accH, 4)
#undef EPI
}

// ---------- O-projection: 2-phase counted-vmcnt pipeline (unchanged from R15) ----------
__global__ __launch_bounds__(512)
void gemm_out_2ph(const u16* __restrict__ A, const u16* __restrict__ Bt,
                  float* __restrict__ C)
{
  __shared__ __align__(16) u16 lds_[3 * 24576];   // 144 KB
  const int t = threadIdx.x, lane = t & 63;
  const int w = t >> 6, wm = w >> 1, wn = w & 1;   // 4M x 2N
  const int r = lane & 15, g = lane >> 4;
  const int m0 = blockIdx.y * 256, n0 = blockIdx.x * 128;

  f32x4 acc[4][4];
  #pragma unroll
  for (int i = 0; i < 4; i++)
    #pragma unroll
    for (int j = 0; j < 4; j++) acc[i][j] = (f32x4){0.f, 0.f, 0.f, 0.f};

  const int srow = t >> 3, sgr = t & 7;
  auto gA = [&](int kt, int bsel, int gi) {
    int row = gi * 64 + srow;
    int sg = sgr ^ (row & 7);
    gload_lds16(A + (size_t)(m0 + row) * HID + kt * 64 + sg * 8,
                lds_ + bsel * 24576 + row * 64 + sgr * 8);
  };
  auto gB = [&](int kt, int bsel, int gi) {
    int row = gi * 64 + srow;
    int sg = sgr ^ (row & 7);
    gload_lds16(Bt + (size_t)(n0 + row) * HID + kt * 64 + sg * 8,
                lds_ + bsel * 24576 + 16384 + row * 64 + sgr * 8);
  };

  FragAB a[4], b[4];
  auto readAB = [&](int bsel, int kk) {
    const u16* Ab = lds_ + bsel * 24576;
    const u16* Bb = Ab + 16384;
    #pragma unroll
    for (int mi = 0; mi < 4; mi++) {
      int row = wm * 64 + mi * 16 + r;
      int pg = (kk * 4 + g) ^ (row & 7);
      a[mi].u4 = *(const uint4*)&Ab[row * 64 + pg * 8];
    }
    #pragma unroll
    for (int ni = 0; ni < 4; ni++) {
      int row = wn * 64 + ni * 16 + r;
      int pg = (kk * 4 + g) ^ (row & 7);
      b[ni].u4 = *(const uint4*)&Bb[row * 64 + pg * 8];
    }
  };

#define MFQ                                                                   \
  __builtin_amdgcn_s_setprio(1);                                              \
  _Pragma("unroll")                                                           \
  for (int mi = 0; mi < 4; mi++)                                              \
    _Pragma("unroll")                                                         \
    for (int ni = 0; ni < 4; ni++)                                            \
      acc[mi][ni] = __builtin_amdgcn_mfma_f32_16x16x32_bf16(a[mi].v, b[ni].v, acc[mi][ni], 0, 0, 0); \
  __builtin_amdgcn_s_setprio(0);

  const int NT = HID / 64;   // 32 K-tiles
  gB(0, 0, 0); gB(0, 0, 1); gA(0, 0, 0); gA(0, 0, 1); gA(0, 0, 2); gA(0, 0, 3);
  gB(1, 1, 0); gB(1, 1, 1); gA(1, 1, 0); gA(1, 1, 1); gA(1, 1, 2); gA(1, 1, 3);
  asm volatile("s_waitcnt vmcnt(6)" ::: "memory");
  __builtin_amdgcn_s_barrier();

  for (int kt = 0; kt < NT; ++kt) {
    const int bsel = kt % 3, nb = (kt + 2) % 3;
    const bool more2 = (kt + 2 < NT);
    readAB(bsel, 0);
    if (more2) { gB(kt + 2, nb, 0); gB(kt + 2, nb, 1); gA(kt + 2, nb, 0); }
    __builtin_amdgcn_s_barrier();
    __builtin_amdgcn_sched_barrier(0);
    MFQ
    __builtin_amdgcn_s_barrier();
    readAB(bsel, 1);
    if (more2) { gA(kt + 2, nb, 1); gA(kt + 2, nb, 2); gA(kt + 2, nb, 3); }
    __builtin_amdgcn_s_barrier();
    __builtin_amdgcn_sched_barrier(0);
    MFQ
    if (more2)            asm volatile("s_waitcnt vmcnt(6)" ::: "memory");
    else if (kt + 1 < NT) asm volatile("s_waitcnt vmcnt(0)" ::: "memory");
    __builtin_amdgcn_s_barrier();
  }
#undef MFQ

  #pragma unroll
  for (int mi = 0; mi < 4; mi++) {
    int row = m0 + wm * 64 + mi * 16 + g * 4;
    #pragma unroll
    for (int ni = 0; ni < 4; ni++) {
      int col = n0 + wn * 64 + ni * 16 + r;
      #pragma unroll
      for (int rr = 0; rr < 4; rr++)
        C[(size_t)(row + rr) * HID + col] = acc[mi][ni][rr];
    }
  }
}

// ---------- MFMA flash attention: KVBLK=128 (half the tiles/barriers of R16) ----------
// QBLK=128 = KVBLK: every wave participates in every tile; only tile jt==qb masks.
// No-max softmax (separable) computed in two 64-key halves to bound registers.
// l accumulated via ones-row MFMA (Vt rows 64..79 constant). Double-buffered
// reg-staged K/V (one barrier per 128-key tile).
__device__ __forceinline__ void attn_block(const u16* __restrict__ Q, const u16* __restrict__ K,
    const u16* __restrict__ VT, u16* __restrict__ O,
    u16* Ks0, u16* Vt0, u16* Ks1, u16* Vt1, int qb, int h, int b)
{
  const int t = threadIdx.x, lane = t & 63, w = t >> 6;
  const int r = lane & 15, g = lane >> 4;
  const int kvh = h >> 2;
  const int base = qb * 128 + w * 32;

  FragAB qf[2][2];
  {
    const u16* Qg = Q + ((size_t)(b * 2048 + base)) * 2048 + h * 64;
    #pragma unroll
    for (int mb = 0; mb < 2; mb++)
      #pragma unroll
      for (int ks = 0; ks < 2; ks++)
        qf[mb][ks].u4 = *(const uint4*)(Qg + (size_t)(mb * 16 + r) * 2048 + ks * 32 + g * 8);
  }

  f32x4 olacc[2];
  f32x4 o[2][4];
  #pragma unroll
  for (int mb = 0; mb < 2; mb++) {
    olacc[mb] = (f32x4){0.f, 0.f, 0.f, 0.f};
    #pragma unroll
    for (int nd = 0; nd < 4; nd++) o[mb][nd] = (f32x4){0.f, 0.f, 0.f, 0.f};
  }

  const u16* Kg0 = K + (size_t)(b * 2048) * 512 + kvh * 64;
  const u16* Vg0 = VT + (size_t)(kvh * 64) * NROW + (size_t)b * 2048;
  const int nt = qb + 1;

  uint4 kr[4], vr[4];   // staging regs: K 128x64, V 64x128
  auto loadt = [&](int jt) {
    #pragma unroll
    for (int i = 0; i < 4; i++) {
      int idx = i * 256 + t;
      kr[i] = *(const uint4*)(Kg0 + (size_t)(jt * 128 + (idx >> 3)) * 512 + (idx & 7) * 8);
      vr[i] = *(const uint4*)(Vg0 + (size_t)(idx >> 4) * NROW + jt * 128 + (idx & 15) * 8);
    }
  };
  auto writet = [&](u16* Ks, u16* Vt) {
    #pragma unroll
    for (int i = 0; i < 4; i++) {
      int idx = i * 256 + t;
      *(uint4*)&Ks[(idx >> 3) * 72 + (idx & 7) * 8] = kr[i];
      *(uint4*)&Vt[(idx >> 4) * 136 + (idx & 15) * 8] = vr[i];
    }
  };

  loadt(0);
  writet(Ks0, Vt0);
  __syncthreads();

  for (int jt = 0; jt < nt; ++jt) {
    u16* Ks = (jt & 1) ? Ks1 : Ks0;
    u16* Vt = (jt & 1) ? Vt1 : Vt0;
    if (jt + 1 < nt) loadt(jt + 1);

    FragAB pa[2][4];
    const bool diag = (jt == qb);
    #pragma unroll
    for (int half = 0; half < 2; ++half) {
      // QK^T for keys [half*64, half*64+64): st[mb][kb][i] = S[mb*16+r][half*64 + kb*16 + g*4 + i]
      f32x4 st[2][4];
      #pragma unroll
      for (int mb = 0; mb < 2; mb++)
        #pragma unroll
        for (int kb = 0; kb < 4; kb++) st[mb][kb] = (f32x4){0.f, 0.f, 0.f, 0.f};
      #pragma unroll
      for (int ks = 0; ks < 2; ks++) {
        FragAB kf[4];
        #pragma unroll
        for (int kb = 0; kb < 4; kb++)
          kf[kb].u4 = *(const uint4*)&Ks[((half * 4 + kb) * 16 + r) * 72 + ks * 32 + g * 8];
        __builtin_amdgcn_s_setprio(1);
        #pragma unroll
        for (int mb = 0; mb < 2; mb++)
          #pragma unroll
          for (int kb = 0; kb < 4; kb++)
            st[mb][kb] = __builtin_amdgcn_mfma_f32_16x16x32_bf16(kf[kb].v, qf[mb][ks].v, st[mb][kb], 0, 0, 0);
        __builtin_amdgcn_s_setprio(0);
      }
      // no-max softmax on this half (separable: fixed m=0)
      #pragma unroll
      for (int mb = 0; mb < 2; mb++) {
        float p[4][4];
        if (diag) {
          const int kdel = half * 64 + g * 4 - w * 32 - mb * 16 - r;
          #pragma unroll
          for (int kb = 0; kb < 4; kb++)
            #pragma unroll
            for (int i = 0; i < 4; i++) {
              float sv = (kdel + kb * 16 + i > 0) ? -1e30f : st[mb][kb][i];
              p[kb][i] = __builtin_exp2f(sv);
            }
        } else {
          #pragma unroll
          for (int kb = 0; kb < 4; kb++)
            #pragma unroll
            for (int i = 0; i < 4; i++)
              p[kb][i] = __builtin_exp2f(st[mb][kb][i]);
        }
        #pragma unroll
        for (int k2 = 0; k2 < 2; k2++) {
          pa[mb][half * 2 + k2].q[0] = make_uint2(cvtpk_bf16(p[2 * k2][0], p[2 * k2][1]),
                                                  cvtpk_bf16(p[2 * k2][2], p[2 * k2][3]));
          pa[mb][half * 2 + k2].q[1] = make_uint2(cvtpk_bf16(p[2 * k2 + 1][0], p[2 * k2 + 1][1]),
                                                  cvtpk_bf16(p[2 * k2 + 1][2], p[2 * k2 + 1][3]));
        }
      }
    }

    // PV: o^T += V^T @ P^T over 4 key-slots; ones-row accumulates l on matrix pipe
    #pragma unroll
    for (int ks = 0; ks < 4; ks++) {
      FragAB vf[4], ve;
      #pragma unroll
      for (int nd = 0; nd < 4; nd++) {
        const u16* bb = &Vt[(nd * 16 + r) * 136 + ks * 32 + g * 4];
        vf[nd].q[0] = *(const uint2*)(bb);
        vf[nd].q[1] = *(const uint2*)(bb + 16);
      }
      {
        const u16* bb = &Vt[(64 + r) * 136 + ks * 32 + g * 4];
        ve.q[0] = *(const uint2*)(bb);
        ve.q[1] = *(const uint2*)(bb + 16);
      }
      __builtin_amdgcn_s_setprio(1);
      #pragma unroll
      for (int mb = 0; mb < 2; mb++) {
        #pragma unroll
        for (int nd = 0; nd < 4; nd++)
          o[mb][nd] = __builtin_amdgcn_mfma_f32_16x16x32_bf16(vf[nd].v, pa[mb][ks].v, o[mb][nd], 0, 0, 0);
        olacc[mb] = __builtin_amdgcn_mfma_f32_16x16x32_bf16(ve.v, pa[mb][ks].v, olacc[mb], 0, 0, 0);
      }
      __builtin_amdgcn_s_setprio(0);
    }

    if (jt + 1 < nt) writet((jt & 1) ? Ks0 : Ks1, (jt & 1) ? Vt0 : Vt1);
    __syncthreads();   // one barrier per 128-key tile
  }

  u16* Og = O + ((size_t)(b * 2048 + base)) * 2048 + h * 64;
  #pragma unroll
  for (int mb = 0; mb < 2; mb++) {
    float l = __shfl(olacc[mb][0], r);   // l lives in g==0 lanes, reg 0
    float inv = 1.f / l;
    #pragma unroll
    for (int nd = 0; nd < 4; nd++) {
      ushort4 hv;
      hv.x = f2bf(o[mb][nd][0] * inv); hv.y = f2bf(o[mb][nd][1] * inv);
      hv.z = f2bf(o[mb][nd][2] * inv); hv.w = f2bf(o[mb][nd][3] * inv);
      *(ushort4*)(Og + (size_t)(mb * 16 + r) * 2048 + nd * 16 + g * 4) = hv;
    }
  }
}

// Paired q-blocks (bx, 15-bx): (bx+1) + (16-bx) = 17 tiles/block constant.
__global__ __launch_bounds__(256)
void attn_mfma(const u16* __restrict__ Q, const u16* __restrict__ K,
               const u16* __restrict__ VT, u16* __restrict__ O)
{
  __shared__ __align__(16) u16 Ks0[128 * 72];   // 18.0 KB
  __shared__ __align__(16) u16 Vt0[80 * 136];   // 21.3 KB (rows 64..79 = const ext)
  __shared__ __align__(16) u16 Ks1[128 * 72];
  __shared__ __align__(16) u16 Vt1[80 * 136];
  // init constant ext rows (row 64 = ones over 128 keys, 65..79 = zero)
  for (int i = threadIdx.x; i < 16 * 136; i += 256) {
    int row = i / 136, col = i % 136;
    u16 v = (row == 0 && col < 128) ? (u16)0x3F80 : (u16)0;
    Vt0[(64 + row) * 136 + col] = v;
    Vt1[(64 + row) * 136 + col] = v;
  }
  const int h = blockIdx.y, b = blockIdx.z;
  attn_block(Q, K, VT, O, Ks0, Vt0, Ks1, Vt1, (int)blockIdx.x, h, b);
  attn_block(Q, K, VT, O, Ks0, Vt0, Ks1, Vt1, 15 - (int)blockIdx.x, h, b);
}

extern "C" void kernel_launch(void* const* d_in, const int* in_sizes, int n_in,
                              void* d_out, int out_size, void* d_ws, size_t ws_size,
                              hipStream_t stream)
{
  (void)in_sizes; (void)n_in; (void)out_size; (void)ws_size;
  const float* X  = (const float*)d_in[0];
  const float* Wq = (const float*)d_in[1];
  const float* Wk = (const float*)d_in[2];
  const float* Wv = (const float*)d_in[3];
  const float* Wo = (const float*)d_in[4];
  float* out = (float*)d_out;

  u16* Xb  = (u16*)d_ws;                         // [4096][2048]
  u16* Qb  = Xb  + (size_t)NROW * HID;           // [4096][2048] (pre-scaled by SC2)
  u16* Kb  = Qb  + (size_t)NROW * HID;           // [4096][512]
  u16* VTb = Kb  + (size_t)NROW * KVH;           // [512][4096]  (V transposed)
  u16* Wqt = VTb + (size_t)NROW * KVH;           // [2048][2048]
  u16* Wkt = Wqt + (size_t)HID * HID;            // [512][2048]
  u16* Wvt = Wkt + (size_t)HID * KVH;            // [512][2048]
  u16* Wot = Wvt + (size_t)HID * KVH;            // [2048][2048]
  u16* AOb = Xb;    // alias: X dead after gemm_8ph

  prep_all<<<dim3(64, 64, 5), 256, 0, stream>>>(X, Xb, Wq, Wk, Wv, Wo, Wqt, Wkt, Wvt, Wot);
  gemm_8ph<<<dim3(12, 16), 512, 0, stream>>>(Xb, Wqt, Wkt, Wvt, Qb, Kb, VTb);
  attn_mfma<<<dim3(8, 32, 2), 256, 0, stream>>>(Qb, Kb, VTb, AOb);
  gemm_out_2ph<<<dim3(16, 16), 512, 0, stream>>>(AOb, Wot, out);
}

// Round 18
// 200.598 us; speedup vs baseline: 1.1453x; 1.1453x over previous
//
#include <hip/hip_runtime.h>

typedef unsigned short u16;
typedef unsigned int u32;
typedef __attribute__((ext_vector_type(8))) short short8_t;
typedef __attribute__((ext_vector_type(4))) float f32x4;

#define HID 2048
#define KVH 512
#define NROW 4096   // B*S
#define SC2 0.18033688011112042f   // (1/sqrt(64)) * log2(e)

__device__ __forceinline__ u16 f2bf(float f){
  u32 u = __builtin_bit_cast(u32, f);
  u += 0x7fffu + ((u >> 16) & 1u);   // round-to-nearest-even
  return (u16)(u >> 16);
}
__device__ __forceinline__ u32 cvtpk_bf16(float lo, float hi){
  u32 r; asm("v_cvt_pk_bf16_f32 %0, %1, %2" : "=v"(r) : "v"(lo), "v"(hi)); return r;
}

union FragAB { short8_t v; uint4 u4; uint2 q[2]; };

__device__ __forceinline__ void gload_lds16(const u16* g, u16* l){
  __builtin_amdgcn_global_load_lds((const __attribute__((address_space(1))) void*)g,
                                   (__attribute__((address_space(3))) void*)l, 16, 0, 0);
}

// ---------- prep: fused fp32->bf16 convert (z=4) + all four W transposes (z=0..3) ----------
__global__ __launch_bounds__(256)
void prep_all(const float* __restrict__ X, u16* __restrict__ Xb,
              const float* __restrict__ Wq, const float* __restrict__ Wk,
              const float* __restrict__ Wv, const float* __restrict__ Wo,
              u16* __restrict__ Tq, u16* __restrict__ Tk,
              u16* __restrict__ Tv, u16* __restrict__ To)
{
  const int z = blockIdx.z;
  if (z == 4) {   // conv: 4096 blocks x 512 float4 = 2M float4 exact
    int bid = blockIdx.y * 64 + blockIdx.x;
    int i0 = bid * 512 + threadIdx.x;
    #pragma unroll
    for (int it = 0; it < 2; ++it) {
      int i = i0 + it * 256;
      float4 v = ((const float4*)X)[i];
      ushort4 hx; hx.x = f2bf(v.x); hx.y = f2bf(v.y); hx.z = f2bf(v.z); hx.w = f2bf(v.w);
      ((ushort4*)Xb)[i] = hx;
    }
    return;
  }
  __shared__ float tile[32][33];
  const float* W; u16* T; int N;
  if (z == 0)      { W = Wq; T = Tq; N = HID; }
  else if (z == 1) { W = Wk; T = Tk; N = KVH; }
  else if (z == 2) { W = Wv; T = Tv; N = KVH; }
  else             { W = Wo; T = To; N = HID; }
  if ((int)blockIdx.x * 32 >= N) return;
  const int tx = threadIdx.x & 31, ty = threadIdx.x >> 5;
  int x = blockIdx.x * 32 + tx;
  int y0 = blockIdx.y * 32;
  #pragma unroll
  for (int j = ty; j < 32; j += 8)
    tile[j][tx] = W[(size_t)(y0 + j) * N + x];
  __syncthreads();
  #pragma unroll
  for (int j = ty; j < 32; j += 8)
    T[(size_t)(blockIdx.x * 32 + j) * HID + y0 + tx] = f2bf(tile[tx][j]);
}

// ---------- 8-phase 256x256 GEMM (fused QKV) — R14-proven ----------
__global__ __launch_bounds__(512)
void gemm_8ph(const u16* __restrict__ A, const u16* __restrict__ B0,
              const u16* __restrict__ B1, const u16* __restrict__ B2,
              u16* __restrict__ C0, u16* __restrict__ C1, u16* __restrict__ C2)
{
  __shared__ __align__(16) u16 lds_[2 * 32768];   // 128 KB
  const int t = threadIdx.x, lane = t & 63;
  const int w = t >> 6, wm = w >> 2, wn = w & 3;   // 2M x 4N
  const int r = lane & 15, g = lane >> 4;
  const int m0 = blockIdx.y * 256;

  const u16* Bt; u16* Cp; int n0, mode;
  {
    const int bx = blockIdx.x;
    if (bx < 8)       { Bt = B0; Cp = C0; n0 = bx * 256;        mode = 0; }
    else if (bx < 10) { Bt = B1; Cp = C1; n0 = (bx - 8) * 256;  mode = 1; }
    else              { Bt = B2; Cp = C2; n0 = (bx - 10) * 256; mode = 2; }
  }

  f32x4 accL[4][4], accH[4][4];
  #pragma unroll
  for (int i = 0; i < 4; i++)
    #pragma unroll
    for (int j = 0; j < 4; j++) {
      accL[i][j] = (f32x4){0.f, 0.f, 0.f, 0.f};
      accH[i][j] = (f32x4){0.f, 0.f, 0.f, 0.f};
    }

  const int srow = t >> 3, sgr = t & 7;
  auto gA = [&](int kt, int gi) {
    int row = gi * 64 + srow;
    int sg = sgr ^ (row & 7);
    gload_lds16(A + (size_t)(m0 + row) * HID + kt * 64 + sg * 8,
                lds_ + (kt & 1) * 32768 + row * 64 + sgr * 8);
  };
  auto gB = [&](int kt, int gi) {
    int row = gi * 64 + srow;
    int sg = sgr ^ (row & 7);
    gload_lds16(Bt + (size_t)(n0 + row) * HID + kt * 64 + sg * 8,
                lds_ + (kt & 1) * 32768 + 16384 + row * 64 + sgr * 8);
  };

  FragAB a[4], b0[4], b1[4];
  auto readA = [&](int kt, int mlo, int kk) {
    const u16* Ab = lds_ + (kt & 1) * 32768;
    #pragma unroll
    for (int i = 0; i < 4; i++) {
      int row = wm * 128 + (mlo + i) * 16 + r;
      int pg = (kk * 4 + g) ^ (row & 7);
      a[i].u4 = *(const uint4*)&Ab[row * 64 + pg * 8];
    }
  };
  auto readB = [&](int kt, int kk, FragAB (&bf)[4]) {
    const u16* Bb = lds_ + (kt & 1) * 32768 + 16384;
    #pragma unroll
    for (int ni = 0; ni < 4; ni++) {
      int row = wn * 64 + ni * 16 + r;
      int pg = (kk * 4 + g) ^ (row & 7);
      bf[ni].u4 = *(const uint4*)&Bb[row * 64 + pg * 8];
    }
  };

#define MFQ(BF, ACC)                                                          \
  __builtin_amdgcn_s_setprio(1);                                              \
  _Pragma("unroll")                                                           \
  for (int mi = 0; mi < 4; mi++)                                              \
    _Pragma("unroll")                                                         \
    for (int ni = 0; ni < 4; ni++)                                            \
      ACC[mi][ni] = __builtin_amdgcn_mfma_f32_16x16x32_bf16(a[mi].v, BF[ni].v, ACC[mi][ni], 0, 0, 0); \
  __builtin_amdgcn_s_setprio(0);

  const int NT = HID / 64;   // 32 K-tiles
  gB(0, 0); gB(0, 1); gB(0, 2); gB(0, 3);
  gA(0, 0); gA(0, 2); gA(0, 1); gA(0, 3);
  asm volatile("s_waitcnt vmcnt(2)" ::: "memory");
  __builtin_amdgcn_s_barrier();

  for (int kt = 0; kt < NT; ++kt) {
    const bool more = (kt + 1 < NT);
    readB(kt, 0, b0); readA(kt, 0, 0);
    if (more) { gB(kt + 1, 0); gB(kt + 1, 1); }
    __builtin_amdgcn_s_barrier();
    __builtin_amdgcn_sched_barrier(0);
    MFQ(b0, accL)
    __builtin_amdgcn_s_barrier();
    readB(kt, 1, b1); readA(kt, 0, 1);
    if (more) { gB(kt + 1, 2); gB(kt + 1, 3); }
    __builtin_amdgcn_s_barrier();
    __builtin_amdgcn_sched_barrier(0);
    MFQ(b1, accL)
    if (more) asm volatile("s_waitcnt vmcnt(4)" ::: "memory");
    else      asm volatile("s_waitcnt vmcnt(0)" ::: "memory");
    __builtin_amdgcn_s_barrier();
    readA(kt, 4, 0);
    if (more) { gA(kt + 1, 0); gA(kt + 1, 2); }
    __builtin_amdgcn_s_barrier();
    __builtin_amdgcn_sched_barrier(0);
    MFQ(b0, accH)
    __builtin_amdgcn_s_barrier();
    readA(kt, 4, 1);
    if (more) { gA(kt + 1, 1); gA(kt + 1, 3); }
    __builtin_amdgcn_s_barrier();
    __builtin_amdgcn_sched_barrier(0);
    MFQ(b1, accH)
    asm volatile("s_waitcnt vmcnt(2)" ::: "memory");
    __builtin_amdgcn_s_barrier();
  }
#undef MFQ

#define EPI(ACC, MOFF)                                                        \
  _Pragma("unroll")                                                           \
  for (int mi = 0; mi < 4; mi++) {                                            \
    int row = m0 + wm * 128 + (mi + MOFF) * 16 + g * 4;                       \
    _Pragma("unroll")                                                         \
    for (int ni = 0; ni < 4; ni++) {                                          \
      int col = n0 + wn * 64 + ni * 16 + r;                                   \
      if (mode == 2) {                                                        \
        ushort4 hv;                                                           \
        hv.x = f2bf(ACC[mi][ni][0]); hv.y = f2bf(ACC[mi][ni][1]);             \
        hv.z = f2bf(ACC[mi][ni][2]); hv.w = f2bf(ACC[mi][ni][3]);             \
        *(ushort4*)&Cp[(size_t)col * NROW + row] = hv;                        \
      } else {                                                                \
        const int Nout = (mode == 0) ? HID : KVH;                             \
        const float sc = (mode == 0) ? SC2 : 1.f;                             \
        _Pragma("unroll")                                                     \
        for (int rr = 0; rr < 4; rr++)                                        \
          Cp[(size_t)(row + rr) * Nout + col] = f2bf(ACC[mi][ni][rr] * sc);   \
      }                                                                       \
    }                                                                         \
  }
  EPI(accL, 0)
  EPI(accH, 4)
#undef EPI
}

// ---------- O-projection: 2-phase counted-vmcnt pipeline (R15-proven) ----------
__global__ __launch_bounds__(512)
void gemm_out_2ph(const u16* __restrict__ A, const u16* __restrict__ Bt,
                  float* __restrict__ C)
{
  __shared__ __align__(16) u16 lds_[3 * 24576];   // 144 KB
  const int t = threadIdx.x, lane = t & 63;
  const int w = t >> 6, wm = w >> 1, wn = w & 1;   // 4M x 2N
  const int r = lane & 15, g = lane >> 4;
  const int m0 = blockIdx.y * 256, n0 = blockIdx.x * 128;

  f32x4 acc[4][4];
  #pragma unroll
  for (int i = 0; i < 4; i++)
    #pragma unroll
    for (int j = 0; j < 4; j++) acc[i][j] = (f32x4){0.f, 0.f, 0.f, 0.f};

  const int srow = t >> 3, sgr = t & 7;
  auto gA = [&](int kt, int bsel, int gi) {
    int row = gi * 64 + srow;
    int sg = sgr ^ (row & 7);
    gload_lds16(A + (size_t)(m0 + row) * HID + kt * 64 + sg * 8,
                lds_ + bsel * 24576 + row * 64 + sgr * 8);
  };
  auto gB = [&](int kt, int bsel, int gi) {
    int row = gi * 64 + srow;
    int sg = sgr ^ (row & 7);
    gload_lds16(Bt + (size_t)(n0 + row) * HID + kt * 64 + sg * 8,
                lds_ + bsel * 24576 + 16384 + row * 64 + sgr * 8);
  };

  FragAB a[4], b[4];
  auto readAB = [&](int bsel, int kk) {
    const u16* Ab = lds_ + bsel * 24576;
    const u16* Bb = Ab + 16384;
    #pragma unroll
    for (int mi = 0; mi < 4; mi++) {
      int row = wm * 64 + mi * 16 + r;
      int pg = (kk * 4 + g) ^ (row & 7);
      a[mi].u4 = *(const uint4*)&Ab[row * 64 + pg * 8];
    }
    #pragma unroll
    for (int ni = 0; ni < 4; ni++) {
      int row = wn * 64 + ni * 16 + r;
      int pg = (kk * 4 + g) ^ (row & 7);
      b[ni].u4 = *(const uint4*)&Bb[row * 64 + pg * 8];
    }
  };

#define MFQ                                                                   \
  __builtin_amdgcn_s_setprio(1);                                              \
  _Pragma("unroll")                                                           \
  for (int mi = 0; mi < 4; mi++)                                              \
    _Pragma("unroll")                                                         \
    for (int ni = 0; ni < 4; ni++)                                            \
      acc[mi][ni] = __builtin_amdgcn_mfma_f32_16x16x32_bf16(a[mi].v, b[ni].v, acc[mi][ni], 0, 0, 0); \
  __builtin_amdgcn_s_setprio(0);

  const int NT = HID / 64;   // 32 K-tiles
  gB(0, 0, 0); gB(0, 0, 1); gA(0, 0, 0); gA(0, 0, 1); gA(0, 0, 2); gA(0, 0, 3);
  gB(1, 1, 0); gB(1, 1, 1); gA(1, 1, 0); gA(1, 1, 1); gA(1, 1, 2); gA(1, 1, 3);
  asm volatile("s_waitcnt vmcnt(6)" ::: "memory");
  __builtin_amdgcn_s_barrier();

  for (int kt = 0; kt < NT; ++kt) {
    const int bsel = kt % 3, nb = (kt + 2) % 3;
    const bool more2 = (kt + 2 < NT);
    readAB(bsel, 0);
    if (more2) { gB(kt + 2, nb, 0); gB(kt + 2, nb, 1); gA(kt + 2, nb, 0); }
    __builtin_amdgcn_s_barrier();
    __builtin_amdgcn_sched_barrier(0);
    MFQ
    __builtin_amdgcn_s_barrier();
    readAB(bsel, 1);
    if (more2) { gA(kt + 2, nb, 1); gA(kt + 2, nb, 2); gA(kt + 2, nb, 3); }
    __builtin_amdgcn_s_barrier();
    __builtin_amdgcn_sched_barrier(0);
    MFQ
    if (more2)            asm volatile("s_waitcnt vmcnt(6)" ::: "memory");
    else if (kt + 1 < NT) asm volatile("s_waitcnt vmcnt(0)" ::: "memory");
    __builtin_amdgcn_s_barrier();
  }
#undef MFQ

  #pragma unroll
  for (int mi = 0; mi < 4; mi++) {
    int row = m0 + wm * 64 + mi * 16 + g * 4;
    #pragma unroll
    for (int ni = 0; ni < 4; ni++) {
      int col = n0 + wn * 64 + ni * 16 + r;
      #pragma unroll
      for (int rr = 0; rr < 4; rr++)
        C[(size_t)(row + rr) * HID + col] = acc[mi][ni][rr];
    }
  }
}

// ---------- MFMA flash attention (R16-exact: best-measured 86.9 µs config) ----------
// KVBLK=64, no-max softmax, l via ones-row MFMA, async-staged dbuf K/V LDS,
// one barrier per tile, paired blocks (constant 34 tiles).
__device__ __forceinline__ void attn_block(const u16* __restrict__ Q, const u16* __restrict__ K,
    const u16* __restrict__ VT, u16* __restrict__ O,
    u16* Ks0, u16* Vt0, u16* Ks1, u16* Vt1, int qb, int h, int b)
{
  const int t = threadIdx.x, lane = t & 63, w = t >> 6;
  const int r = lane & 15, g = lane >> 4;
  const int kvh = h >> 2;
  const int base = qb * 128 + w * 32;

  FragAB qf[2][2];
  {
    const u16* Qg = Q + ((size_t)(b * 2048 + base)) * 2048 + h * 64;
    #pragma unroll
    for (int mb = 0; mb < 2; mb++)
      #pragma unroll
      for (int ks = 0; ks < 2; ks++)
        qf[mb][ks].u4 = *(const uint4*)(Qg + (size_t)(mb * 16 + r) * 2048 + ks * 32 + g * 8);
  }

  f32x4 olacc[2];
  f32x4 o[2][4];
  #pragma unroll
  for (int mb = 0; mb < 2; mb++) {
    olacc[mb] = (f32x4){0.f, 0.f, 0.f, 0.f};
    #pragma unroll
    for (int nd = 0; nd < 4; nd++) o[mb][nd] = (f32x4){0.f, 0.f, 0.f, 0.f};
  }

  const u16* Kg0 = K + (size_t)(b * 2048) * 512 + kvh * 64;
  const u16* Vg0 = VT + (size_t)(kvh * 64) * NROW + (size_t)b * 2048;
  const int nt = 2 * qb + 2;
  const int srow = t >> 3, scol = (t & 7) * 8;

  uint4 kr0, kr1, vr0, vr1;
  auto loadt = [&](int jt) {
    const u16* Kg = Kg0 + (size_t)(jt * 64) * 512;
    kr0 = *(const uint4*)(Kg + (size_t)srow * 512 + scol);
    kr1 = *(const uint4*)(Kg + (size_t)(srow + 32) * 512 + scol);
    const u16* Vg = Vg0 + jt * 64;
    vr0 = *(const uint4*)(Vg + (size_t)srow * NROW + scol);
    vr1 = *(const uint4*)(Vg + (size_t)(srow + 32) * NROW + scol);
  };
  auto writet = [&](u16* Ks, u16* Vt) {
    *(uint4*)&Ks[srow * 72 + scol] = kr0;
    *(uint4*)&Ks[(srow + 32) * 72 + scol] = kr1;
    *(uint4*)&Vt[srow * 72 + scol] = vr0;
    *(uint4*)&Vt[(srow + 32) * 72 + scol] = vr1;
  };

  loadt(0);
  writet(Ks0, Vt0);
  __syncthreads();

  for (int jt = 0; jt < nt; ++jt) {
    u16* Ks = (jt & 1) ? Ks1 : Ks0;
    u16* Vt = (jt & 1) ? Vt1 : Vt0;
    if (jt + 1 < nt) loadt(jt + 1);

    if (jt * 64 <= base + 31) {
      f32x4 st[2][4];
      #pragma unroll
      for (int mb = 0; mb < 2; mb++)
        #pragma unroll
        for (int kb = 0; kb < 4; kb++) st[mb][kb] = (f32x4){0.f, 0.f, 0.f, 0.f};
      #pragma unroll
      for (int ks = 0; ks < 2; ks++) {
        FragAB kf[4];
        #pragma unroll
        for (int kb = 0; kb < 4; kb++)
          kf[kb].u4 = *(const uint4*)&Ks[(kb * 16 + r) * 72 + ks * 32 + g * 8];
        __builtin_amdgcn_s_setprio(1);
        #pragma unroll
        for (int mb = 0; mb < 2; mb++)
          #pragma unroll
          for (int kb = 0; kb < 4; kb++)
            st[mb][kb] = __builtin_amdgcn_mfma_f32_16x16x32_bf16(kf[kb].v, qf[mb][ks].v, st[mb][kb], 0, 0, 0);
        __builtin_amdgcn_s_setprio(0);
      }

      FragAB pa[2][2];
      #pragma unroll
      for (int mb = 0; mb < 2; mb++) {
        const int rowg = base + mb * 16 + r;
        float p[4][4];
        if (jt * 64 + 63 > base + mb * 16) {
          const int kdel = jt * 64 + g * 4 - rowg;
          #pragma unroll
          for (int kb = 0; kb < 4; kb++)
            #pragma unroll
            for (int i = 0; i < 4; i++) {
              float sv = (kdel + kb * 16 + i > 0) ? -1e30f : st[mb][kb][i];
              p[kb][i] = __builtin_exp2f(sv);
            }
        } else {
          #pragma unroll
          for (int kb = 0; kb < 4; kb++)
            #pragma unroll
            for (int i = 0; i < 4; i++)
              p[kb][i] = __builtin_exp2f(st[mb][kb][i]);
        }
        #pragma unroll
        for (int ks = 0; ks < 2; ks++) {
          pa[mb][ks].q[0] = make_uint2(cvtpk_bf16(p[2 * ks][0], p[2 * ks][1]),
                                       cvtpk_bf16(p[2 * ks][2], p[2 * ks][3]));
          pa[mb][ks].q[1] = make_uint2(cvtpk_bf16(p[2 * ks + 1][0], p[2 * ks + 1][1]),
                                       cvtpk_bf16(p[2 * ks + 1][2], p[2 * ks + 1][3]));
        }
      }

      #pragma unroll
      for (int ks = 0; ks < 2; ks++) {
        FragAB vf[4], ve;
        #pragma unroll
        for (int nd = 0; nd < 4; nd++) {
          const u16* bb = &Vt[(nd * 16 + r) * 72 + ks * 32 + g * 4];
          vf[nd].q[0] = *(const uint2*)(bb);
          vf[nd].q[1] = *(const uint2*)(bb + 16);
        }
        {
          const u16* bb = &Vt[(64 + r) * 72 + ks * 32 + g * 4];
          ve.q[0] = *(const uint2*)(bb);
          ve.q[1] = *(const uint2*)(bb + 16);
        }
        __builtin_amdgcn_s_setprio(1);
        #pragma unroll
        for (int mb = 0; mb < 2; mb++) {
          #pragma unroll
          for (int nd = 0; nd < 4; nd++)
            o[mb][nd] = __builtin_amdgcn_mfma_f32_16x16x32_bf16(vf[nd].v, pa[mb][ks].v, o[mb][nd], 0, 0, 0);
          olacc[mb] = __builtin_amdgcn_mfma_f32_16x16x32_bf16(ve.v, pa[mb][ks].v, olacc[mb], 0, 0, 0);
        }
        __builtin_amdgcn_s_setprio(0);
      }
    }

    if (jt + 1 < nt) writet((jt & 1) ? Ks0 : Ks1, (jt & 1) ? Vt0 : Vt1);
    __syncthreads();
  }

  u16* Og = O + ((size_t)(b * 2048 + base)) * 2048 + h * 64;
  #pragma unroll
  for (int mb = 0; mb < 2; mb++) {
    float l = __shfl(olacc[mb][0], r);   // l lives in g==0 lanes, reg 0
    float inv = 1.f / l;
    #pragma unroll
    for (int nd = 0; nd < 4; nd++) {
      ushort4 hv;
      hv.x = f2bf(o[mb][nd][0] * inv); hv.y = f2bf(o[mb][nd][1] * inv);
      hv.z = f2bf(o[mb][nd][2] * inv); hv.w = f2bf(o[mb][nd][3] * inv);
      *(ushort4*)(Og + (size_t)(mb * 16 + r) * 2048 + nd * 16 + g * 4) = hv;
    }
  }
}

__global__ __launch_bounds__(256)
void attn_mfma(const u16* __restrict__ Q, const u16* __restrict__ K,
               const u16* __restrict__ VT, u16* __restrict__ O)
{
  __shared__ __align__(16) u16 Ks0[64 * 72];
  __shared__ __align__(16) u16 Vt0[80 * 72];
  __shared__ __align__(16) u16 Ks1[64 * 72];
  __shared__ __align__(16) u16 Vt1[80 * 72];
  // init constant ext rows (row 64 = ones, 65..79 = zero) once per block
  for (int i = threadIdx.x; i < 16 * 72; i += 256) {
    int row = i / 72, col = i % 72;
    u16 v = (row == 0 && col < 64) ? (u16)0x3F80 : (u16)0;
    Vt0[(64 + row) * 72 + col] = v;
    Vt1[(64 + row) * 72 + col] = v;
  }
  const int h = blockIdx.y, b = blockIdx.z;
  attn_block(Q, K, VT, O, Ks0, Vt0, Ks1, Vt1, (int)blockIdx.x, h, b);
  attn_block(Q, K, VT, O, Ks0, Vt0, Ks1, Vt1, 15 - (int)blockIdx.x, h, b);
}

extern "C" void kernel_launch(void* const* d_in, const int* in_sizes, int n_in,
                              void* d_out, int out_size, void* d_ws, size_t ws_size,
                              hipStream_t stream)
{
  (void)in_sizes; (void)n_in; (void)out_size; (void)ws_size;
  const float* X  = (const float*)d_in[0];
  const float* Wq = (const float*)d_in[1];
  const float* Wk = (const float*)d_in[2];
  const float* Wv = (const float*)d_in[3];
  const float* Wo = (const float*)d_in[4];
  float* out = (float*)d_out;

  u16* Xb  = (u16*)d_ws;                         // [4096][2048]
  u16* Qb  = Xb  + (size_t)NROW * HID;           // [4096][2048] (pre-scaled by SC2)
  u16* Kb  = Qb  + (size_t)NROW * HID;           // [4096][512]
  u16* VTb = Kb  + (size_t)NROW * KVH;           // [512][4096]  (V transposed)
  u16* Wqt = VTb + (size_t)NROW * KVH;           // [2048][2048]
  u16* Wkt = Wqt + (size_t)HID * HID;            // [512][2048]
  u16* Wvt = Wkt + (size_t)HID * KVH;            // [512][2048]
  u16* Wot = Wvt + (size_t)HID * KVH;            // [2048][2048]
  u16* AOb = Xb;    // alias: X dead after gemm_8ph

  prep_all<<<dim3(64, 64, 5), 256, 0, stream>>>(X, Xb, Wq, Wk, Wv, Wo, Wqt, Wkt, Wvt, Wot);
  gemm_8ph<<<dim3(12, 16), 512, 0, stream>>>(Xb, Wqt, Wkt, Wvt, Qb, Kb, VTb);
  attn_mfma<<<dim3(8, 32, 2), 256, 0, stream>>>(Qb, Kb, VTb, AOb);
  gemm_out_2ph<<<dim3(16, 16), 512, 0, stream>>>(AOb, Wot, out);
}